// Round 3
// baseline (454.455 us; speedup 1.0000x reference)
//
#include <hip/hip_runtime.h>
#include <hip/hip_bf16.h>

// Problem constants (fixed by setup_inputs)
#define E_    8
#define DIN   2048
#define DOUT  2048
#define N_TOK 4096
#define NK    8192
#define R_    16
#define KEXT  2112            // 2048 + 16 (LoRA rank tail) + 48 zero pad, %64==0
#define KT_N  (KEXT / 64)     // 33 K-tiles
#define BM    256
#define BN    256
#define MT_MAX 40             // worst-case sum_e ceil(Me/256) = 32 + 7 (+1 slack)

typedef __bf16 bf16x8 __attribute__((ext_vector_type(8)));
typedef float  f32x4  __attribute__((ext_vector_type(4)));

static __device__ __forceinline__ void gld16(const void* g, void* l) {
  __builtin_amdgcn_global_load_lds(
      (const __attribute__((address_space(1))) unsigned int*)g,
      (__attribute__((address_space(3))) unsigned int*)l, 16, 0, 0);
}

static __device__ __forceinline__ unsigned short f2bfu(float f) {
  union { float f; unsigned int u; } v; v.f = f;
  unsigned int r = v.u + 0x7fffu + ((v.u >> 16) & 1u);  // round-to-nearest-even
  return (unsigned short)(r >> 16);
}

// ---- fused prep: Wbe build | token gather | lora_A convert (independent, one launch) ----
__global__ void __launch_bounds__(256)
k_prep(const float* __restrict__ w, const float* __restrict__ lb,
       unsigned short* __restrict__ wbe,
       const float* __restrict__ la, unsigned short* __restrict__ Ab,
       const float* __restrict__ x, const int* __restrict__ ssi,
       const float* __restrict__ gates, const int* __restrict__ kptr,
       unsigned short* __restrict__ Xe, float* __restrict__ gate,
       int* __restrict__ tok) {
  const int b = blockIdx.x, tid = threadIdx.x;
  if (b < 4096) {                                   // ---- wconv ----
    const int wv = tid >> 6, ln = tid & 63;
    const long long row = ((long long)b << 2) | wv; // e*DOUT + n
    const float4* src  = (const float4*)(w + row * DIN);
    const float4* lsrc = (const float4*)(lb + row * R_);
    ushort4* dst = (ushort4*)(wbe + row * KEXT);
    for (int u = ln; u < KEXT / 4; u += 64) {
      float4 v;
      if (u < 512)       v = src[u];
      else if (u < 516)  v = lsrc[u - 512];
      else               v = make_float4(0.f, 0.f, 0.f, 0.f);
      ushort4 o;
      o.x = f2bfu(v.x); o.y = f2bfu(v.y); o.z = f2bfu(v.z); o.w = f2bfu(v.w);
      dst[u] = o;
    }
  } else if (b < 12288) {                           // ---- gather ----
    const int s = b - 4096;
    int ssv = ssi[s];
    int kk = kptr[0];
    int t = ssv / kk, sl = ssv - t * kk;
    if (tid == 0) { gate[s] = gates[t * kk + sl]; tok[s] = t; }
    const float4* src = (const float4*)(x + (long long)t * DIN);
    ushort4* dst = (ushort4*)(Xe + (long long)s * KEXT);
    for (int i = tid; i < 512; i += 256) {
      float4 v = src[i];
      ushort4 o;
      o.x = f2bfu(v.x); o.y = f2bfu(v.y); o.z = f2bfu(v.z); o.w = f2bfu(v.w);
      dst[i] = o;
    }
    if (tid < 12) {   // zero cols 2064..2111 (XA slot 2048..2063 filled by k_xa)
      ushort4 z; z.x = z.y = z.z = z.w = 0;
      dst[516 + tid] = z;
    }
  } else {                                          // ---- aconv ----
    const int i = ((b - 12288) << 8) + tid;         // 65536 float4 total
    float4 v = ((const float4*)la)[i];
    ushort4 o;
    o.x = f2bfu(v.x); o.y = f2bfu(v.y); o.z = f2bfu(v.z); o.w = f2bfu(v.w);
    ((ushort4*)Ab)[i] = o;
  }
}

// ---- XA tail via MFMA: Xe[s][2048+r] = bf16( 2 * dot(x_s, lora_A[e][r]) ) ----
__global__ void __launch_bounds__(256)
k_xa(unsigned short* __restrict__ Xe, const unsigned short* __restrict__ Ab,
     const int* __restrict__ eoff) {
  __shared__ f32x4 red[4][64];
  int tile = blockIdx.x;
  int off_prev = 0, e = -1, m_start = 0, m_end = 0, acc_t = 0;
#pragma unroll
  for (int i = 0; i < E_; i++) {
    int oe = eoff[i];
    int te = (oe - off_prev + 15) >> 4;
    if (e < 0 && tile < acc_t + te) {
      e = i; m_start = off_prev + (tile - acc_t) * 16; m_end = oe;
    }
    acc_t += te; off_prev = oe;
  }
  if (e < 0) return;
  const int tid = threadIdx.x;
  const int wv = tid >> 6, lane = tid & 63;
  const int l15 = lane & 15, quad = lane >> 4;
  int arow = m_start + l15; if (arow >= m_end) arow = m_end - 1;  // clamp partial tile
  const unsigned short* xp = Xe + (long long)arow * KEXT + wv * 512 + quad * 8;
  const unsigned short* bp = Ab + ((long long)e * R_ + l15) * DIN + wv * 512 + quad * 8;
  f32x4 acc = (f32x4){0.f, 0.f, 0.f, 0.f};
#pragma unroll 8
  for (int k0 = 0; k0 < 512; k0 += 32) {
    bf16x8 a = *(const bf16x8*)(xp + k0);
    bf16x8 b = *(const bf16x8*)(bp + k0);
    acc = __builtin_amdgcn_mfma_f32_16x16x32_bf16(a, b, acc, 0, 0, 0);
  }
  red[wv][lane] = acc;
  __syncthreads();
  if (wv == 0) {
    f32x4 s = red[0][lane] + red[1][lane] + red[2][lane] + red[3][lane];
#pragma unroll
    for (int t = 0; t < 4; t++) {
      int slot = m_start + quad * 4 + t;
      if (slot < m_end)
        Xe[(long long)slot * KEXT + 2048 + l15] = f2bfu(2.0f * s[t]);
    }
  }
}

// ---- grouped GEMM, 256x256 tile, 8 waves, dbuf BK=64, PHASE-PIPELINED (T3+T4+T5) ----
// 4 phases per K-tile; phase p computes mi{2p,2p+1} x all ni x both ks (16 MFMA),
// B fragments (bfr[8]) loaded once per tile and held in registers.
// Staging for tile t+1 is spread over tile t's phases in CONSUMPTION order:
//   ph0: B rows 0-127 (sweeps 0,1)   ph1: B rows 128-255 (2,3)
//   ph2: A rows 0-63,128-191 (4,5)   ph3: A rows 64-127,192-255 (6,7)
// Counted waits (per-wave, each wave issues all 8 sweeps itself):
//   tile boundary: vmcnt(2)  -> retires sweeps 0-5 of tile t (issue->wait >= 2 phases)
//   phase 2:       vmcnt(4)  -> retires sweeps 6,7 of tile t (3-phase distance)
// Never vmcnt(0) in the main loop (last tile only). s_barrier every phase keeps
// skew <= 1 phase (overwrite-safety verified per region). setprio around MFMA (T5).
__global__ void __launch_bounds__(512, 2)
k_gemm(const unsigned short* __restrict__ Xe, const unsigned short* __restrict__ Wbe,
       const float* __restrict__ gate, const int* __restrict__ tok,
       const int* __restrict__ eoff, float* __restrict__ out) {
  __shared__ alignas(16) unsigned short sA[2][BM * 64];   // 64 KB
  __shared__ alignas(16) unsigned short sB[2][BN * 64];   // 64 KB
  __shared__ float gs[BM];
  __shared__ int   ts[BM];

  const int id  = blockIdx.x;          // 320 blocks
  const int nt  = id & 7;              // one n-tile per XCD slot
  const int mt  = id >> 3;             // 0..39
  const int n_start = nt << 8;

  // m-tile scan, BM=256
  int off_prev = 0, e = -1, m_start = 0, m_end = 0, acc_t = 0;
#pragma unroll
  for (int i = 0; i < E_; i++) {
    int oe = eoff[i];
    int te = (oe - off_prev + 255) >> 8;
    if (e < 0 && mt < acc_t + te) {
      e = i; m_start = off_prev + (mt - acc_t) * 256; m_end = oe;
    }
    acc_t += te;
    off_prev = oe;
  }
  if (e < 0) return;

  const int tid = threadIdx.x;
  const int w = tid >> 6, lane = tid & 63;
  const int wm = w >> 2, wn = w & 3;              // 2M x 4N waves, 128x64 out each
  const int quad = lane >> 4, l15 = lane & 15;
  const int srow = lane >> 3;                     // row within 8-row staging chunk
  const int scol = ((lane & 7) ^ srow) * 8;       // SWIZZLED source bf16 col (BK=64)
  const int kx0 = ((0 | quad) ^ (l15 & 7)) << 3;  // ks=0 swizzled read col
  const int kx1 = ((4 | quad) ^ (l15 & 7)) << 3;  // ks=1

  if (tid < 256) {   // stage gates/tokens; drained by prologue waitcnt
    int gm = m_start + tid; if (gm >= m_end) gm = m_end - 1;
    gs[tid] = gate[gm];
    ts[tid] = tok[gm];
  }

  f32x4 acc[8][4];
#pragma unroll
  for (int mi = 0; mi < 8; mi++)
#pragma unroll
    for (int ni = 0; ni < 4; ni++)
      acc[mi][ni] = (f32x4){0.f, 0.f, 0.f, 0.f};

  const unsigned short* Wb = Wbe + (long long)e * DOUT * KEXT;

  // one staging sweep (1 gld16/thread). s_ is a compile-time literal 0..7.
  // s<4: B rows s*64..+64 ; s>=4: A rows in consumption order 0,128,64,192 (+64).
#define SWEEP(buf_, kt_, s_)                                                        \
  do {                                                                              \
    const int k0s_ = (kt_) * 64;                                                    \
    if ((s_) < 4) {                                                                 \
      const int c_ = ((s_) << 3) + w;                                               \
      const int rt_ = (c_ << 3) + srow;                                             \
      gld16(Wb + (long long)(n_start + rt_) * KEXT + k0s_ + scol,                   \
            &sB[buf_][(c_ << 9) + (lane << 3)]);                                    \
    } else {                                                                        \
      const int cb_ = (((s_) - 4) & 1) * 16 + ((((s_) - 4) >> 1) & 1) * 8;          \
      const int c_ = cb_ + w;                                                       \
      const int rt_ = (c_ << 3) + srow;                                             \
      int ga_ = m_start + rt_; if (ga_ >= m_end) ga_ = m_end - 1;                   \
      gld16(Xe + (long long)ga_ * KEXT + k0s_ + scol,                               \
            &sA[buf_][(c_ << 9) + (lane << 3)]);                                    \
    }                                                                               \
  } while (0)

  // read af[4] for phase p_, then 16 MFMA (mi = 2p_, 2p_+1)
#define PHASE(p_)                                                                   \
  {                                                                                 \
    _Pragma("unroll")                                                               \
    for (int dm = 0; dm < 2; dm++) {                                                \
      const int row_ = (wm * 128 + ((p_) * 2 + dm) * 16 + l15) * 64;                \
      af[dm * 2 + 0] = *(const bf16x8*)&sA[b][row_ + kx0];                          \
      af[dm * 2 + 1] = *(const bf16x8*)&sA[b][row_ + kx1];                          \
    }                                                                               \
    asm volatile("s_waitcnt lgkmcnt(0)" ::: "memory");                              \
    __builtin_amdgcn_sched_barrier(0);                                              \
    __builtin_amdgcn_s_setprio(1);                                                  \
    _Pragma("unroll")                                                               \
    for (int dm = 0; dm < 2; dm++)                                                  \
      _Pragma("unroll")                                                             \
      for (int ni = 0; ni < 4; ni++) {                                              \
        acc[(p_) * 2 + dm][ni] = __builtin_amdgcn_mfma_f32_16x16x32_bf16(           \
            af[dm * 2 + 0], bfr[ni * 2 + 0], acc[(p_) * 2 + dm][ni], 0, 0, 0);      \
        acc[(p_) * 2 + dm][ni] = __builtin_amdgcn_mfma_f32_16x16x32_bf16(           \
            af[dm * 2 + 1], bfr[ni * 2 + 1], acc[(p_) * 2 + dm][ni], 0, 0, 0);      \
      }                                                                             \
    __builtin_amdgcn_s_setprio(0);                                                  \
  }

  // prologue: clean vm/lgkm slate (gs/ts + gate/tok retired), then tile-0 sweeps
  asm volatile("s_waitcnt vmcnt(0) lgkmcnt(0)" ::: "memory");
  SWEEP(0, 0, 0); SWEEP(0, 0, 1); SWEEP(0, 0, 2); SWEEP(0, 0, 3);
  SWEEP(0, 0, 4); SWEEP(0, 0, 5); SWEEP(0, 0, 6); SWEEP(0, 0, 7);

  for (int kt = 0; kt < KT_N; ++kt) {
    const int b = kt & 1, nb = b ^ 1;
    const bool more = (kt + 1 < KT_N);
    bf16x8 af[4], bfr[8];

    // ---------- phase 0 ----------
    if (more) asm volatile("s_waitcnt vmcnt(2)" ::: "memory");
    else      asm volatile("s_waitcnt vmcnt(0)" ::: "memory");
    __builtin_amdgcn_s_barrier();
    __builtin_amdgcn_sched_barrier(0);
    if (more) { SWEEP(nb, kt + 1, 0); SWEEP(nb, kt + 1, 1); }
#pragma unroll
    for (int ni = 0; ni < 4; ni++) {
      const int brow_ = (wn * 64 + ni * 16 + l15) * 64;
      bfr[ni * 2 + 0] = *(const bf16x8*)&sB[b][brow_ + kx0];
      bfr[ni * 2 + 1] = *(const bf16x8*)&sB[b][brow_ + kx1];
    }
    PHASE(0)

    // ---------- phase 1 ----------
    __builtin_amdgcn_s_barrier();
    __builtin_amdgcn_sched_barrier(0);
    if (more) { SWEEP(nb, kt + 1, 2); SWEEP(nb, kt + 1, 3); }
    PHASE(1)

    // ---------- phase 2 ----------
    if (more) asm volatile("s_waitcnt vmcnt(4)" ::: "memory");
    else      asm volatile("s_waitcnt vmcnt(0)" ::: "memory");
    __builtin_amdgcn_s_barrier();
    __builtin_amdgcn_sched_barrier(0);
    if (more) { SWEEP(nb, kt + 1, 4); SWEEP(nb, kt + 1, 5); }
    PHASE(2)

    // ---------- phase 3 ----------
    __builtin_amdgcn_s_barrier();
    __builtin_amdgcn_sched_barrier(0);
    if (more) { SWEEP(nb, kt + 1, 6); SWEEP(nb, kt + 1, 7); }
    PHASE(3)
  }
#undef SWEEP
#undef PHASE

  // ---- epilogue: gate + atomic scatter (LoRA already in acc via K-tail) ----
#pragma unroll
  for (int mi = 0; mi < 8; mi++) {
    const int rbase = wm * 128 + mi * 16 + quad * 4;
#pragma unroll
    for (int t4 = 0; t4 < 4; t4++) {
      const int row = rbase + t4;
      if (m_start + row >= m_end) continue;    // partial tile guard
      const float g = gs[row];
      float* orow = out + (long long)ts[row] * DOUT + n_start + wn * 64 + l15;
#pragma unroll
      for (int ni = 0; ni < 4; ni++)
        atomicAdd(orow + ni * 16, acc[mi][ni][t4] * g);  // exactly k=2 adds/elem
    }
  }
}

extern "C" void kernel_launch(void* const* d_in, const int* in_sizes, int n_in,
                              void* d_out, int out_size, void* d_ws, size_t ws_size,
                              hipStream_t stream) {
  (void)in_sizes; (void)n_in; (void)out_size; (void)ws_size;
  const float* inputs = (const float*)d_in[0];
  const float* weight = (const float*)d_in[1];
  const float* lora_A = (const float*)d_in[2];
  const float* lora_B = (const float*)d_in[3];
  const float* gates  = (const float*)d_in[4];
  const int* sei  = (const int*)d_in[5];
  const int* ssi  = (const int*)d_in[6];
  const int* eoff = (const int*)d_in[7];
  const int* kptr = (const int*)d_in[8];
  (void)sei;
  float* out = (float*)d_out;

  // workspace layout (~104.4 MB)
  unsigned char* ws = (unsigned char*)d_ws;
  unsigned short* Wbe = (unsigned short*)ws;                 // 8*2048*2112*2 = 69,206,016 B
  unsigned short* Xe  = (unsigned short*)(ws + 69206016);    // 8192*2112*2   = 34,603,008 B
  unsigned short* Ab  = (unsigned short*)(ws + 103809024);   // 8*16*2048*2   =    524,288 B
  float* gate = (float*)(ws + 104333312);                    // 8192*4
  int*   tok  = (int*)(ws + 104366080);                      // 8192*4

  hipMemsetAsync(d_out, 0, (size_t)N_TOK * DOUT * sizeof(float), stream);
  k_prep<<<4096 + 8192 + 256, 256, 0, stream>>>(weight, lora_B, Wbe, lora_A, Ab,
                                                inputs, ssi, gates, kptr, Xe, gate, tok);
  k_xa<<<519, 256, 0, stream>>>(Xe, Ab, eoff);
  k_gemm<<<MT_MAX * 8, 512, 0, stream>>>(Xe, Wbe, gate, tok, eoff, out);
}

// Round 4
// 393.455 us; speedup vs baseline: 1.1550x; 1.1550x over previous
//
#include <hip/hip_runtime.h>
#include <hip/hip_bf16.h>

// Problem constants (fixed by setup_inputs)
#define E_    8
#define DIN   2048
#define DOUT  2048
#define N_TOK 4096
#define NK    8192
#define R_    16
#define KEXT  2112            // 2048 + 16 (LoRA rank tail) + 48 zero pad, %64==0
#define KT_N  (KEXT / 64)     // 33 K-tiles

#define XA_B     519          // sum ceil(Me/16) <= 519 (xa blocks first: longest)
#define WCONV_B  4096
#define GATHER_B 8192

typedef __bf16 bf16x8 __attribute__((ext_vector_type(8)));
typedef float  f32x4  __attribute__((ext_vector_type(4)));
typedef unsigned short u16x8 __attribute__((ext_vector_type(8)));

static __device__ __forceinline__ void gld16(const void* g, void* l) {
  __builtin_amdgcn_global_load_lds(
      (const __attribute__((address_space(1))) unsigned int*)g,
      (__attribute__((address_space(3))) unsigned int*)l, 16, 0, 0);
}

static __device__ __forceinline__ unsigned short f2bfu(float f) {
  union { float f; unsigned int u; } v; v.f = f;
  unsigned int r = v.u + 0x7fffu + ((v.u >> 16) & 1u);  // round-to-nearest-even
  return (unsigned short)(r >> 16);
}

static __device__ __forceinline__ bf16x8 cvt8(float4 a, float4 b) {
  u16x8 u;
  u[0] = f2bfu(a.x); u[1] = f2bfu(a.y); u[2] = f2bfu(a.z); u[3] = f2bfu(a.w);
  u[4] = f2bfu(b.x); u[5] = f2bfu(b.y); u[6] = f2bfu(b.z); u[7] = f2bfu(b.w);
  return __builtin_bit_cast(bf16x8, u);
}

// ---- fully-parallel prep: xa | wconv | gather in ONE launch (no serial drain) ----
// xa no longer reads Xe/Ab: it recomputes token rows from ssi and converts
// inputs/lora_A fp32->bf16 IN REGISTER, so it is independent of the gather blocks.
// Disjoint Xe bytes: gather writes cols [0,2048)+[2064,2112); xa writes [2048,2064).
__global__ void __launch_bounds__(256)
k_prep(const float* __restrict__ w, const float* __restrict__ lb,
       unsigned short* __restrict__ wbe,
       const float* __restrict__ la,
       const float* __restrict__ x, const int* __restrict__ ssi,
       const float* __restrict__ gates, const int* __restrict__ kptr,
       unsigned short* __restrict__ Xe, float* __restrict__ gate,
       int* __restrict__ tok, const int* __restrict__ eoff) {
  const int b = blockIdx.x, tid = threadIdx.x;
  if (b < XA_B) {                                   // ---- XA tail ----
    __shared__ f32x4 red[4][64];
    int off_prev = 0, e = -1, m_start = 0, m_end = 0, acc_t = 0;
#pragma unroll
    for (int i = 0; i < E_; i++) {
      int oe = eoff[i];
      int te = (oe - off_prev + 15) >> 4;
      if (e < 0 && b < acc_t + te) {
        e = i; m_start = off_prev + (b - acc_t) * 16; m_end = oe;
      }
      acc_t += te; off_prev = oe;
    }
    if (e < 0) return;
    const int wv = tid >> 6, lane = tid & 63;
    const int l15 = lane & 15, quad = lane >> 4;
    int arow = m_start + l15; if (arow >= m_end) arow = m_end - 1;  // clamp
    const int kk = kptr[0];
    const int trow = ssi[arow] / kk;                // token row for this slot
    const float* xp = x  + (long long)trow * DIN + wv * 512 + quad * 8;
    const float* ap = la + ((long long)e * R_ + l15) * DIN + wv * 512 + quad * 8;
    f32x4 acc = (f32x4){0.f, 0.f, 0.f, 0.f};
#pragma unroll 4
    for (int k0 = 0; k0 < 512; k0 += 32) {
      float4 x0 = *(const float4*)(xp + k0);
      float4 x1 = *(const float4*)(xp + k0 + 4);
      float4 a0 = *(const float4*)(ap + k0);
      float4 a1 = *(const float4*)(ap + k0 + 4);
      acc = __builtin_amdgcn_mfma_f32_16x16x32_bf16(cvt8(x0, x1), cvt8(a0, a1),
                                                    acc, 0, 0, 0);
    }
    red[wv][lane] = acc;
    __syncthreads();
    if (wv == 0) {
      f32x4 s = red[0][lane] + red[1][lane] + red[2][lane] + red[3][lane];
#pragma unroll
      for (int t = 0; t < 4; t++) {
        int slot = m_start + quad * 4 + t;
        if (slot < m_end)
          Xe[(long long)slot * KEXT + 2048 + l15] = f2bfu(2.0f * s[t]);
      }
    }
  } else if (b < XA_B + WCONV_B) {                  // ---- wconv ----
    const int wv = tid >> 6, ln = tid & 63;
    const long long row = (((long long)(b - XA_B)) << 2) | wv;   // e*DOUT + n
    const float4* src  = (const float4*)(w + row * DIN);
    const float4* lsrc = (const float4*)(lb + row * R_);
    ushort4* dst = (ushort4*)(wbe + row * KEXT);
    for (int u = ln; u < KEXT / 4; u += 64) {
      float4 v;
      if (u < 512)       v = src[u];
      else if (u < 516)  v = lsrc[u - 512];
      else               v = make_float4(0.f, 0.f, 0.f, 0.f);
      ushort4 o;
      o.x = f2bfu(v.x); o.y = f2bfu(v.y); o.z = f2bfu(v.z); o.w = f2bfu(v.w);
      dst[u] = o;
    }
  } else {                                          // ---- gather ----
    const int s = b - XA_B - WCONV_B;
    int ssv = ssi[s];
    int kk = kptr[0];
    int t = ssv / kk, sl = ssv - t * kk;
    if (tid == 0) { gate[s] = gates[t * kk + sl]; tok[s] = t; }
    const float4* src = (const float4*)(x + (long long)t * DIN);
    ushort4* dst = (ushort4*)(Xe + (long long)s * KEXT);
    for (int i = tid; i < 512; i += 256) {
      float4 v = src[i];
      ushort4 o;
      o.x = f2bfu(v.x); o.y = f2bfu(v.y); o.z = f2bfu(v.z); o.w = f2bfu(v.w);
      dst[i] = o;
    }
    if (tid < 12) {   // zero cols 2064..2111 (cols 2048..2063 written by xa blocks)
      ushort4 z; z.x = z.y = z.z = z.w = 0;
      dst[516 + tid] = z;
    }
  }
}

// ---- grouped GEMM, 128x128 tile, 8 WAVES (64x32 out each), max-TLP variant ----
// Diagnosis r0-r3: staging rate scales with resident waves/CU (7 TB/s @~16w vs
// 3.6 TB/s @8w), schedule-invariant -> bound by per-CU outstanding-requests x L3
// latency. Lever: halve per-wave registers (acc 4x2 f32x4 = 32 AGPR vs 64) and
// drop gs/ts LDS (exactly 32KB) so more blocks co-reside (~3 blk/CU x 8 waves
// ~= 24 waves/CU vs r0's ~12). Same proven 2-barrier drain loop + XOR swizzle.
__global__ void __launch_bounds__(512)
k_gemm(const unsigned short* __restrict__ Xe, const unsigned short* __restrict__ Wbe,
       const float* __restrict__ gate, const int* __restrict__ tok,
       const int* __restrict__ eoff, float* __restrict__ out) {
  __shared__ alignas(16) unsigned short sAB[2 * 128 * 64];  // A tile | B tile, 32 KB

  const int id = blockIdx.x;                 // 1152 blocks
  const int xcd = id & 7, local = id >> 3;   // local 0..143
  const int mt = local % 72;
  const int nt = (xcd << 1) | (local / 72);  // 0..15
  const int n_start = nt << 7;

  // m-tile scan: mt covers sum(ceil(Me/128)) <= 71
  int off_prev = 0, e = -1, m_start = 0, m_end = 0, acc_t = 0;
#pragma unroll
  for (int i = 0; i < E_; i++) {
    int oe = eoff[i];
    int te = (oe - off_prev + 127) >> 7;
    if (e < 0 && mt < acc_t + te) {
      e = i; m_start = off_prev + (mt - acc_t) * 128; m_end = oe;
    }
    acc_t += te;
    off_prev = oe;
  }
  if (e < 0) return;

  const int tid = threadIdx.x;
  const int w = tid >> 6, lane = tid & 63;   // 8 waves
  const int wm = w >> 2, wn = w & 3;         // 2M x 4N waves, 64x32 out each
  const int quad = lane >> 4, l15 = lane & 15;
  const int srow = lane >> 3;                // row within 8-row staging chunk
  const int scol = ((lane & 7) ^ srow) * 8;  // SWIZZLED source bf16 col within BK=64

  f32x4 acc[4][2];
#pragma unroll
  for (int mi = 0; mi < 4; mi++)
#pragma unroll
    for (int ni = 0; ni < 2; ni++)
      acc[mi][ni] = (f32x4){0.f, 0.f, 0.f, 0.f};

  const unsigned short* Wb = Wbe + (long long)e * DOUT * KEXT;

  for (int kt = 0; kt < KT_N; kt++) {
    const int k0 = kt * 64;
#pragma unroll
    for (int j = 0; j < 4; j++) {
      int c = w * 4 + j;                // chunk 0..31: 0-15 A, 16-31 B (1KB each)
      int rt = (c & 15) * 8 + srow;     // row-in-tile 0..127
      const unsigned short* src;
      if (c < 16) {
        int ga = m_start + rt; if (ga >= m_end) ga = m_end - 1;  // clamp partial
        src = Xe + (long long)ga * KEXT + k0 + scol;
      } else {
        src = Wb + (long long)(n_start + rt) * KEXT + k0 + scol;
      }
      gld16(src, &sAB[c * 512 + lane * 8]);
    }
    __syncthreads();
#pragma unroll
    for (int ks = 0; ks < 2; ks++) {
      // swizzled read: colchunk kc = ks*4+quad lives at slot kc^(row&7)
      const int kx = (((ks << 2) | quad) ^ (l15 & 7)) << 3;
      bf16x8 af[4], bfr[2];
#pragma unroll
      for (int mi = 0; mi < 4; mi++)
        af[mi] = *(const bf16x8*)&sAB[(wm * 64 + mi * 16 + l15) * 64 + kx];
#pragma unroll
      for (int ni = 0; ni < 2; ni++)
        bfr[ni] = *(const bf16x8*)&sAB[8192 + (wn * 32 + ni * 16 + l15) * 64 + kx];
#pragma unroll
      for (int mi = 0; mi < 4; mi++)
#pragma unroll
        for (int ni = 0; ni < 2; ni++)
          acc[mi][ni] = __builtin_amdgcn_mfma_f32_16x16x32_bf16(
              af[mi], bfr[ni], acc[mi][ni], 0, 0, 0);
    }
    __syncthreads();
  }

  // ---- epilogue: gate + atomic scatter (gate/tok straight from global) ----
#pragma unroll
  for (int mi = 0; mi < 4; mi++) {
#pragma unroll
    for (int t4 = 0; t4 < 4; t4++) {
      const int row = wm * 64 + mi * 16 + quad * 4 + t4;
      if (m_start + row >= m_end) continue;    // partial tile guard
      const int rg = m_start + row;
      const float g = gate[rg];                // lanes of a quad share rg: broadcast
      float* orow = out + (long long)tok[rg] * DOUT + n_start + wn * 32 + l15;
#pragma unroll
      for (int ni = 0; ni < 2; ni++)
        atomicAdd(orow + ni * 16, acc[mi][ni][t4] * g);  // exactly k=2 adds/elem
    }
  }
}

extern "C" void kernel_launch(void* const* d_in, const int* in_sizes, int n_in,
                              void* d_out, int out_size, void* d_ws, size_t ws_size,
                              hipStream_t stream) {
  (void)in_sizes; (void)n_in; (void)out_size; (void)ws_size;
  const float* inputs = (const float*)d_in[0];
  const float* weight = (const float*)d_in[1];
  const float* lora_A = (const float*)d_in[2];
  const float* lora_B = (const float*)d_in[3];
  const float* gates  = (const float*)d_in[4];
  const int* sei  = (const int*)d_in[5];
  const int* ssi  = (const int*)d_in[6];
  const int* eoff = (const int*)d_in[7];
  const int* kptr = (const int*)d_in[8];
  (void)sei;
  float* out = (float*)d_out;

  // workspace layout (~104.4 MB)
  unsigned char* ws = (unsigned char*)d_ws;
  unsigned short* Wbe = (unsigned short*)ws;                 // 8*2048*2112*2 = 69,206,016 B
  unsigned short* Xe  = (unsigned short*)(ws + 69206016);    // 8192*2112*2   = 34,603,008 B
  float* gate = (float*)(ws + 104333312);                    // 8192*4
  int*   tok  = (int*)(ws + 104366080);                      // 8192*4

  hipMemsetAsync(d_out, 0, (size_t)N_TOK * DOUT * sizeof(float), stream);
  k_prep<<<XA_B + WCONV_B + GATHER_B, 256, 0, stream>>>(
      weight, lora_B, Wbe, lora_A, inputs, ssi, gates, kptr, Xe, gate, tok, eoff);
  k_gemm<<<1152, 512, 0, stream>>>(Xe, Wbe, gate, tok, eoff, out);
}